// Round 14
// baseline (98.832 us; speedup 1.0000x reference)
//
#include <hip/hip_runtime.h>
#include <hip/hip_bf16.h>

// Problem constants (B=2, S=2048, D=512, H=8, hd=64)
constexpr int Bc = 2, Sc = 2048, Dc = 512, Hc = 8, HDc = 64;
constexpr int Mtot = Bc * Sc;    // 4096
constexpr size_t HEADMAT = (size_t)Bc * Hc * Sc * HDc;  // 2M elems
// softmax in log2 domain
constexpr float SC2  = 0.18033688011112042f;   // 0.125 * log2(e)
constexpr float NEG2 = 14426.950408889634f;    // 10000 * log2(e)

typedef __attribute__((ext_vector_type(8)))  short          short8;
typedef __attribute__((ext_vector_type(8)))  unsigned short ushort8;
typedef __attribute__((ext_vector_type(4)))  float          f32x4;
typedef __attribute__((ext_vector_type(16))) float          f32x16;

#define MFMA16 __builtin_amdgcn_mfma_f32_16x16x32_bf16
#define MFMA32 __builtin_amdgcn_mfma_f32_32x32x16_bf16

static __device__ __forceinline__ unsigned short f32_to_bf16_bits(float f) {
    unsigned int u = __builtin_bit_cast(unsigned int, f);
    unsigned int r = u + 0x7FFFu + ((u >> 16) & 1u);   // RNE
    return (unsigned short)(r >> 16);
}
static __device__ __forceinline__ unsigned int pkbf(float a, float b) {
    return (unsigned int)f32_to_bf16_bits(a) |
           ((unsigned int)f32_to_bf16_bits(b) << 16);
}

// ---------------------------------------------------------------------------
// x f32 -> bf16
// ---------------------------------------------------------------------------
__global__ __launch_bounds__(256)
void convert_x(const float* __restrict__ x, unsigned short* __restrict__ Xb, int n)
{
    const int i = (blockIdx.x * 256 + threadIdx.x) * 4;
    if (i >= n) return;
    const float4 v = *(const float4*)(x + i);
    ushort4 o;
    o.x = f32_to_bf16_bits(v.x);
    o.y = f32_to_bf16_bits(v.y);
    o.z = f32_to_bf16_bits(v.z);
    o.w = f32_to_bf16_bits(v.w);
    *(ushort4*)(Xb + i) = o;
}

// ---------------------------------------------------------------------------
// W -> W^T bf16
// ---------------------------------------------------------------------------
__global__ __launch_bounds__(256)
void transpose_w(const float* __restrict__ W0, const float* __restrict__ W1,
                 const float* __restrict__ W2, const float* __restrict__ W3,
                 unsigned short* __restrict__ Wt)
{
    __shared__ float T[64][65];
    const int z = blockIdx.z;
    const float* Wp = (z == 0) ? W0 : (z == 1) ? W1 : (z == 2) ? W2 : W3;
    unsigned short* Op = Wt + (size_t)z * 512 * 512;

    const int kt = blockIdx.y * 64, nt = blockIdx.x * 64;
    const int t = threadIdx.x;
    const int r  = t >> 2, c4 = (t & 3) * 16;

    #pragma unroll
    for (int i = 0; i < 4; ++i) {
        const float4 v = *(const float4*)(Wp + (size_t)(kt + r) * 512 + nt + c4 + 4 * i);
        T[r][c4 + 4*i + 0] = v.x;
        T[r][c4 + 4*i + 1] = v.y;
        T[r][c4 + 4*i + 2] = v.z;
        T[r][c4 + 4*i + 3] = v.w;
    }
    __syncthreads();

    const int n = t >> 2, k4 = (t & 3) * 16;
    #pragma unroll
    for (int i = 0; i < 4; ++i) {
        ushort4 o;
        o.x = f32_to_bf16_bits(T[k4 + 4*i + 0][n]);
        o.y = f32_to_bf16_bits(T[k4 + 4*i + 1][n]);
        o.z = f32_to_bf16_bits(T[k4 + 4*i + 2][n]);
        o.w = f32_to_bf16_bits(T[k4 + 4*i + 3][n]);
        *(ushort4*)(Op + (size_t)(nt + n) * 512 + kt + k4 + 4 * i) = o;
    }
}

// ---------------------------------------------------------------------------
// Tiled bf16 MFMA GEMM (unchanged, verified R9-R13).
// ---------------------------------------------------------------------------
template<bool HEADOUT>
__global__ __launch_bounds__(256)
void gemm_tile(const unsigned short* __restrict__ Xb,
               const unsigned short* __restrict__ Wt,
               const float* __restrict__ b0, const float* __restrict__ b1,
               const float* __restrict__ b2,
               unsigned short* __restrict__ Hout,
               float* __restrict__ Yf)
{
    __shared__ short As[128 * 32];
    __shared__ short Bs[64 * 32];

    const int lane = threadIdx.x & 63, wave = threadIdx.x >> 6;
    const int c = lane & 15, g = lane >> 4;
    const int wr = wave >> 1, wc = wave & 1;
    const int z = blockIdx.z;
    const unsigned short* Wp = Wt + (size_t)z * 512 * 512;
    const float* bp = (z == 0) ? b0 : (z == 1) ? b1 : b2;
    const int bm = blockIdx.y * 128;
    const int bn = blockIdx.x * 64;

    const int srow = lane >> 2;
    const int scol = (lane & 3) * 8;

    f32x4 acc[4][2] = {};

    for (int k0 = 0; k0 < 512; k0 += 32) {
        __syncthreads();
        #pragma unroll
        for (int i = 0; i < 2; ++i) {
            const int row = (wave * 2 + i) * 16 + srow;
            const short8 v = *(const short8*)(Xb + (size_t)(bm + row) * 512 + k0 + scol);
            *(short8*)(&As[row * 32 + scol]) = v;
        }
        {
            const int row = wave * 16 + srow;
            const short8 v = *(const short8*)(Wp + (size_t)(bn + row) * 512 + k0 + scol);
            *(short8*)(&Bs[row * 32 + scol]) = v;
        }
        __syncthreads();

        short8 a[4], bfr[2];
        #pragma unroll
        for (int mi = 0; mi < 4; ++mi)
            a[mi] = *(const short8*)(&As[(wr * 64 + mi * 16 + c) * 32 + g * 8]);
        #pragma unroll
        for (int ni = 0; ni < 2; ++ni)
            bfr[ni] = *(const short8*)(&Bs[(wc * 32 + ni * 16 + c) * 32 + g * 8]);
        #pragma unroll
        for (int mi = 0; mi < 4; ++mi)
            #pragma unroll
            for (int ni = 0; ni < 2; ++ni)
                acc[mi][ni] = MFMA16(a[mi], bfr[ni], acc[mi][ni], 0, 0, 0);
    }

    #pragma unroll
    for (int mi = 0; mi < 4; ++mi) {
        #pragma unroll
        for (int ni = 0; ni < 2; ++ni) {
            const int n = bn + wc * 32 + ni * 16 + c;
            const float bias = bp[n];
            float v[4];
            #pragma unroll
            for (int r = 0; r < 4; ++r)
                v[r] = fmaxf(acc[mi][ni][r] + bias, 0.0f);
            const int mbase = bm + wr * 64 + mi * 16 + 4 * g;
            if constexpr (HEADOUT) {
                const int bb = mbase >> 11, ss = mbase & 2047;
                const int hh = n >> 6, hd = n & 63;
                #pragma unroll
                for (int r = 0; r < 4; ++r)
                    Hout[(size_t)z * HEADMAT +
                         (((size_t)(bb * Hc + hh) * Sc + ss + r) * HDc + hd)] =
                        f32_to_bf16_bits(v[r]);
            } else {
                #pragma unroll
                for (int r = 0; r < 4; ++r)
                    Yf[(size_t)(mbase + r) * 512 + n] = v[r];
            }
        }
    }
}

// ---------------------------------------------------------------------------
// Split-K flash attention, v10: 32x32 MFMA (R13-verified body) + MIRROR
// PAIRING across heads for uniform block duration (R12-verified idea).
// 512 blocks. Block (hp = bid&7, t = bid>>3) processes:
//   tile t     of head (b = hp>>2, h = 2*(hp&3))     -- nT = t+1
//   tile 63-t  of head (b = hp>>2, h = 2*(hp&3)+1)   -- nT = 64-t
// Sum = 65 tile-iters for EVERY block -> no causal tail. Head-pair per XCD
// (bid&7 round-robin): 2 heads' K+V = 1MB << 4MB L2.
// Per tile: swapped-QK 32x32 (S[key][q=lane&31]), in-lane softmax (16 keys
// in-lane + shfl_xor(32)), packed-P half-exchange, PV as O^T = mfma(V^T, P),
// wave-private LDS V gather; per-tile combine from LDS overlay + store.
// ---------------------------------------------------------------------------
__global__ __launch_bounds__(256)
void attn_mfma(const short* __restrict__ Qh, const short* __restrict__ Kh,
               const short* __restrict__ Vh, const int* __restrict__ mask,
               unsigned short* __restrict__ Ob)
{
    // per-wave 8448B: loop = V stage [32][72] bf16 (4608B used);
    // overlay = Lacc[64][33] f32 (8448B). Lml separate 256B/wave.
    __shared__ __align__(16) char smem[4 * 8448 + 4 * 256];

    const int lane = threadIdx.x & 63;
    const int wave = threadIdx.x >> 6;
    const int bid  = blockIdx.x;          // 512 blocks
    const int hp   = bid & 7;             // head-pair = XCD slot
    const int tt   = bid >> 3;            // 0..63
    const int b    = hp >> 2;
    const int h0   = 2 * (hp & 3);
    const int r32  = lane & 31;
    const int hi   = lane >> 5;

    char*  wreg = smem + wave * 8448;
    short* vst  = (short*)wreg;                       // [32][72]
    float* Lml  = (float*)(smem + 4 * 8448 + wave * 256);

    const int* mb = mask + b * Sc;

    // first unmasked key (block-uniform; same b for both tiles)
    int fb = Sc;
    for (int base = 0; base < Sc; base += 64) {
        unsigned long long bal = __ballot(mb[base + lane] != 0);
        if (bal) { fb = base + (__ffsll(bal) - 1); break; }
    }

    const int vrow = lane >> 1, vcol = (lane & 1) * 32;

    #pragma unroll
    for (int tile = 0; tile < 2; ++tile) {
        const int q0 = (tile == 0) ? tt * 32 : (63 - tt) * 32;
        const int h  = h0 + tile;
        const size_t headoff = (size_t)(b * Hc + h) * Sc * HDc;
        const short* Qp = Qh + headoff;
        const short* Kp = Kh + headoff;
        const short* Vp = Vh + headoff;

        const int kmax = (fb <= q0) ? (q0 + 32) : Sc;
        const int kend = (kmax + 31) & ~31;
        const int nT   = kend >> 5;
        const int tpw  = (nT + 3) >> 2;
        const int kbeg = wave * tpw * 32;
        const int kfin = min(kend, kbeg + tpw * 32);

        // Q fragments (B-operand): Q[q=r32][d = 16j + 8hi + e]
        short8 qf[4];
        #pragma unroll
        for (int j = 0; j < 4; ++j)
            qf[j] = *(const short8*)(Qp + (size_t)(q0 + r32) * HDc + j * 16 + hi * 8);

        f32x16 acc0 = {0,0,0,0,0,0,0,0,0,0,0,0,0,0,0,0};
        f32x16 acc1 = {0,0,0,0,0,0,0,0,0,0,0,0,0,0,0,0};
        float m = -1e30f, l = 0.0f;

        for (int k0 = kbeg; k0 < kfin; k0 += 32) {
            // --- V stage loads issued early
            const short* vsrc = Vp + (size_t)(k0 + vrow) * HDc + vcol;
            const ushort8 vr0 = *(const ushort8*)(vsrc + 0);
            const ushort8 vr1 = *(const ushort8*)(vsrc + 8);
            const ushort8 vr2 = *(const ushort8*)(vsrc + 16);
            const ushort8 vr3 = *(const ushort8*)(vsrc + 24);

            // --- K fragments (A-operand): K[key=r32][d = 16j + 8hi + e]
            f32x16 s = {0,0,0,0,0,0,0,0,0,0,0,0,0,0,0,0};
            #pragma unroll
            for (int j = 0; j < 4; ++j) {
                const short8 kf =
                    *(const short8*)(Kp + (size_t)(k0 + r32) * HDc + j * 16 + hi * 8);
                s = MFMA32(kf, qf[j], s, 0, 0, 0);
            }

            // --- padding-mask bits (ballot -> wave-uniform word)
            const unsigned long long bal = __ballot(mb[k0 + r32] != 0);
            const unsigned int mloc = ((unsigned int)bal) >> (4 * hi);

            float e[16];
            float tmax = -1e30f;
            if (k0 + 31 > q0) {   // diagonal tile: causal compares needed
                #pragma unroll
                for (int r = 0; r < 16; ++r) {
                    const int cr0 = (r & 3) + 8 * (r >> 2);
                    float ev = s[r] * SC2;
                    if (!((mloc >> cr0) & 1))            ev -= NEG2;
                    if (k0 + cr0 + 4 * hi > q0 + r32)    ev -= NEG2;
                    e[r] = ev;
                    tmax = fmaxf(tmax, ev);
                }
            } else {
                #pragma unroll
                for (int r = 0; r < 16; ++r) {
                    const int cr0 = (r & 3) + 8 * (r >> 2);
                    float ev = s[r] * SC2;
                    if (!((mloc >> cr0) & 1))            ev -= NEG2;
                    e[r] = ev;
                    tmax = fmaxf(tmax, ev);
                }
            }
            tmax = fmaxf(tmax, __shfl_xor(tmax, 32));   // full-row max

            if (__any(tmax > m)) {
                const float mn   = fmaxf(m, tmax);
                const float corr = __builtin_exp2f(m - mn);
                m = mn; l *= corr;
                acc0 *= corr;            // q = lane&31: lane-local rescale
                acc1 *= corr;
            }

            float ps = 0.f;
            #pragma unroll
            for (int r = 0; r < 16; ++r) {
                e[r] = __builtin_exp2f(e[r] - m);   // e[] now holds p
                ps += e[r];
            }
            l += ps;   // own-half partial; cross-half added at end

            // --- pack P pairs and exchange across lane-halves
            const unsigned int A0 = pkbf(e[0],  e[1]),  B0 = pkbf(e[2],  e[3]);
            const unsigned int C0 = pkbf(e[4],  e[5]),  D0 = pkbf(e[6],  e[7]);
            const unsigned int A1 = pkbf(e[8],  e[9]),  B1 = pkbf(e[10], e[11]);
            const unsigned int C1 = pkbf(e[12], e[13]), D1 = pkbf(e[14], e[15]);
            const unsigned int A0s = (unsigned int)__shfl_xor((int)A0, 32);
            const unsigned int B0s = (unsigned int)__shfl_xor((int)B0, 32);
            const unsigned int C0s = (unsigned int)__shfl_xor((int)C0, 32);
            const unsigned int D0s = (unsigned int)__shfl_xor((int)D0, 32);
            const unsigned int A1s = (unsigned int)__shfl_xor((int)A1, 32);
            const unsigned int B1s = (unsigned int)__shfl_xor((int)B1, 32);
            const unsigned int C1s = (unsigned int)__shfl_xor((int)C1, 32);
            const unsigned int D1s = (unsigned int)__shfl_xor((int)D1, 32);

            union { unsigned int u[4]; short8 s8; } P0, P1;
            P0.u[0] = hi ? C0s : A0;  P0.u[1] = hi ? D0s : B0;
            P0.u[2] = hi ? C0  : A0s; P0.u[3] = hi ? D0  : B0s;
            P1.u[0] = hi ? C1s : A1;  P1.u[1] = hi ? D1s : B1;
            P1.u[2] = hi ? C1  : A1s; P1.u[3] = hi ? D1  : B1s;

            // --- V regs -> wave-private LDS
            short* vdst = vst + vrow * 72 + vcol;
            *(ushort8*)(vdst + 0)  = vr0;
            *(ushort8*)(vdst + 8)  = vr1;
            *(ushort8*)(vdst + 16) = vr2;
            *(ushort8*)(vdst + 24) = vr3;

            // --- PV: O^T += V^T_frag x P_frag (A-row = d, B-col = q)
            short8 va;
            #pragma unroll
            for (int e8 = 0; e8 < 8; ++e8)
                va[e8] = vst[(8 * hi + e8) * 72 + r32];
            acc0 = MFMA32(va, P0.s8, acc0, 0, 0, 0);
            #pragma unroll
            for (int e8 = 0; e8 < 8; ++e8)
                va[e8] = vst[(16 + 8 * hi + e8) * 72 + r32];
            acc0 = MFMA32(va, P1.s8, acc0, 0, 0, 0);
            #pragma unroll
            for (int e8 = 0; e8 < 8; ++e8)
                va[e8] = vst[(8 * hi + e8) * 72 + 32 + r32];
            acc1 = MFMA32(va, P0.s8, acc1, 0, 0, 0);
            #pragma unroll
            for (int e8 = 0; e8 < 8; ++e8)
                va[e8] = vst[(16 + 8 * hi + e8) * 72 + 32 + r32];
            acc1 = MFMA32(va, P1.s8, acc1, 0, 0, 0);
        }

        l += __shfl_xor(l, 32);   // full-row denominator for this wave

        // dump partials into OWN overlay region (V stage dead)
        {
            float* Lacc = (float*)wreg;   // [64][33]
            #pragma unroll
            for (int r = 0; r < 16; ++r) {
                Lacc[lane * 33 + r]      = acc0[r];
                Lacc[lane * 33 + 16 + r] = acc1[r];
            }
            if (lane < 32) { Lml[lane] = m; Lml[32 + lane] = l; }
        }
        __syncthreads();

        // combine: per-lane weights (q = r32); wave w handles regs [8w,8w+8)
        float mu[4], lu[4], M = -1e30f;
        #pragma unroll
        for (int u = 0; u < 4; ++u) {
            const float* LmlU = (const float*)(smem + 4 * 8448 + u * 256);
            mu[u] = LmlU[r32];
            lu[u] = LmlU[32 + r32];
            M = fmaxf(M, mu[u]);
        }
        float wgt[4], L = 0.f;
        #pragma unroll
        for (int u = 0; u < 4; ++u) {
            wgt[u] = __builtin_exp2f(mu[u] - M);
            L += wgt[u] * lu[u];
        }
        const float invL = 1.0f / L;

        #pragma unroll
        for (int jj = 0; jj < 8; ++jj) {
            const int j = wave * 8 + jj;
            float o = 0.f;
            #pragma unroll
            for (int u = 0; u < 4; ++u)
                o += wgt[u] * ((const float*)(smem + u * 8448))[lane * 33 + j];
            const int j16 = j & 15;
            const int d = (j16 & 3) + 8 * (j16 >> 2) + 4 * hi + 32 * (j >> 4);
            Ob[(size_t)(b * Sc + q0 + r32) * Dc + h * HDc + d] =
                f32_to_bf16_bits(o * invL);
        }
        __syncthreads();   // protect LDS overlay before next tile's V stage
    }
}

// ---------------------------------------------------------------------------
extern "C" void kernel_launch(void* const* d_in, const int* in_sizes, int n_in,
                              void* d_out, int out_size, void* d_ws, size_t ws_size,
                              hipStream_t stream) {
    const float* x  = (const float*)d_in[0];
    const int* mask = (const int*)d_in[1];
    const float* Wq = (const float*)d_in[2];
    const float* bq = (const float*)d_in[3];
    const float* Wk = (const float*)d_in[4];
    const float* bk = (const float*)d_in[5];
    const float* Wv = (const float*)d_in[6];
    const float* bv = (const float*)d_in[7];
    const float* Wo = (const float*)d_in[8];
    const float* bo = (const float*)d_in[9];
    float* out = (float*)d_out;   // reference output dtype is float32

    unsigned short* Xb = (unsigned short*)d_ws;          // 4 MB
    unsigned short* Wt = Xb + (size_t)Mtot * 512;        // 2 MB
    unsigned short* Qh = Wt + (size_t)4 * 512 * 512;     // head-major
    unsigned short* Kh = Qh + HEADMAT;
    unsigned short* Vh = Kh + HEADMAT;
    unsigned short* Ob = Vh + HEADMAT;

    convert_x<<<dim3((Mtot * 512) / 1024), dim3(256), 0, stream>>>(
        x, Xb, Mtot * 512);
    transpose_w<<<dim3(8, 8, 4), dim3(256), 0, stream>>>(Wq, Wk, Wv, Wo, Wt);
    gemm_tile<true><<<dim3(8, Mtot / 128, 3), dim3(256), 0, stream>>>(
        Xb, Wt, bq, bk, bv, Qh, nullptr);
    attn_mfma<<<dim3(512), dim3(256), 0, stream>>>(
        (const short*)Qh, (const short*)Kh, (const short*)Vh, mask, Ob);
    gemm_tile<false><<<dim3(8, Mtot / 128, 1), dim3(256), 0, stream>>>(
        Ob, Wt + (size_t)3 * 512 * 512, bo, bo, bo, nullptr, out);
}

// Round 15
// 97.490 us; speedup vs baseline: 1.0138x; 1.0138x over previous
//
#include <hip/hip_runtime.h>
#include <hip/hip_bf16.h>

// Problem constants (B=2, S=2048, D=512, H=8, hd=64)
constexpr int Bc = 2, Sc = 2048, Dc = 512, Hc = 8, HDc = 64;
constexpr int Mtot = Bc * Sc;    // 4096
constexpr size_t HEADMAT = (size_t)Bc * Hc * Sc * HDc;  // 2M elems
// softmax in log2 domain
constexpr float SC2  = 0.18033688011112042f;   // 0.125 * log2(e)
constexpr float NEG2 = 14426.950408889634f;    // 10000 * log2(e)

typedef __attribute__((ext_vector_type(8)))  short          short8;
typedef __attribute__((ext_vector_type(8)))  unsigned short ushort8;
typedef __attribute__((ext_vector_type(4)))  float          f32x4;
typedef __attribute__((ext_vector_type(16))) float          f32x16;

#define MFMA16 __builtin_amdgcn_mfma_f32_16x16x32_bf16
#define MFMA32 __builtin_amdgcn_mfma_f32_32x32x16_bf16

static __device__ __forceinline__ unsigned short f32_to_bf16_bits(float f) {
    unsigned int u = __builtin_bit_cast(unsigned int, f);
    unsigned int r = u + 0x7FFFu + ((u >> 16) & 1u);   // RNE
    return (unsigned short)(r >> 16);
}
static __device__ __forceinline__ unsigned int pkbf(float a, float b) {
    return (unsigned int)f32_to_bf16_bits(a) |
           ((unsigned int)f32_to_bf16_bits(b) << 16);
}

// ---------------------------------------------------------------------------
// x f32 -> bf16
// ---------------------------------------------------------------------------
__global__ __launch_bounds__(256)
void convert_x(const float* __restrict__ x, unsigned short* __restrict__ Xb, int n)
{
    const int i = (blockIdx.x * 256 + threadIdx.x) * 4;
    if (i >= n) return;
    const float4 v = *(const float4*)(x + i);
    ushort4 o;
    o.x = f32_to_bf16_bits(v.x);
    o.y = f32_to_bf16_bits(v.y);
    o.z = f32_to_bf16_bits(v.z);
    o.w = f32_to_bf16_bits(v.w);
    *(ushort4*)(Xb + i) = o;
}

// ---------------------------------------------------------------------------
// W -> W^T bf16
// ---------------------------------------------------------------------------
__global__ __launch_bounds__(256)
void transpose_w(const float* __restrict__ W0, const float* __restrict__ W1,
                 const float* __restrict__ W2, const float* __restrict__ W3,
                 unsigned short* __restrict__ Wt)
{
    __shared__ float T[64][65];
    const int z = blockIdx.z;
    const float* Wp = (z == 0) ? W0 : (z == 1) ? W1 : (z == 2) ? W2 : W3;
    unsigned short* Op = Wt + (size_t)z * 512 * 512;

    const int kt = blockIdx.y * 64, nt = blockIdx.x * 64;
    const int t = threadIdx.x;
    const int r  = t >> 2, c4 = (t & 3) * 16;

    #pragma unroll
    for (int i = 0; i < 4; ++i) {
        const float4 v = *(const float4*)(Wp + (size_t)(kt + r) * 512 + nt + c4 + 4 * i);
        T[r][c4 + 4*i + 0] = v.x;
        T[r][c4 + 4*i + 1] = v.y;
        T[r][c4 + 4*i + 2] = v.z;
        T[r][c4 + 4*i + 3] = v.w;
    }
    __syncthreads();

    const int n = t >> 2, k4 = (t & 3) * 16;
    #pragma unroll
    for (int i = 0; i < 4; ++i) {
        ushort4 o;
        o.x = f32_to_bf16_bits(T[k4 + 4*i + 0][n]);
        o.y = f32_to_bf16_bits(T[k4 + 4*i + 1][n]);
        o.z = f32_to_bf16_bits(T[k4 + 4*i + 2][n]);
        o.w = f32_to_bf16_bits(T[k4 + 4*i + 3][n]);
        *(ushort4*)(Op + (size_t)(nt + n) * 512 + kt + k4 + 4 * i) = o;
    }
}

// ---------------------------------------------------------------------------
// Tiled bf16 MFMA GEMM. HEADOUT: Q,K (z=0,1) head-major [z][B][H][S][64];
// V (z=2) head-TRANSPOSED [B][H][64][S] (R5/R8-verified epilogue) so the
// attention PV A-fragments are direct coalesced global loads.
// ---------------------------------------------------------------------------
template<bool HEADOUT>
__global__ __launch_bounds__(256)
void gemm_tile(const unsigned short* __restrict__ Xb,
               const unsigned short* __restrict__ Wt,
               const float* __restrict__ b0, const float* __restrict__ b1,
               const float* __restrict__ b2,
               unsigned short* __restrict__ Hout,
               float* __restrict__ Yf)
{
    __shared__ short As[128 * 32];
    __shared__ short Bs[64 * 32];

    const int lane = threadIdx.x & 63, wave = threadIdx.x >> 6;
    const int c = lane & 15, g = lane >> 4;
    const int wr = wave >> 1, wc = wave & 1;
    const int z = blockIdx.z;
    const unsigned short* Wp = Wt + (size_t)z * 512 * 512;
    const float* bp = (z == 0) ? b0 : (z == 1) ? b1 : b2;
    const int bm = blockIdx.y * 128;
    const int bn = blockIdx.x * 64;

    const int srow = lane >> 2;
    const int scol = (lane & 3) * 8;

    f32x4 acc[4][2] = {};

    for (int k0 = 0; k0 < 512; k0 += 32) {
        __syncthreads();
        #pragma unroll
        for (int i = 0; i < 2; ++i) {
            const int row = (wave * 2 + i) * 16 + srow;
            const short8 v = *(const short8*)(Xb + (size_t)(bm + row) * 512 + k0 + scol);
            *(short8*)(&As[row * 32 + scol]) = v;
        }
        {
            const int row = wave * 16 + srow;
            const short8 v = *(const short8*)(Wp + (size_t)(bn + row) * 512 + k0 + scol);
            *(short8*)(&Bs[row * 32 + scol]) = v;
        }
        __syncthreads();

        short8 a[4], bfr[2];
        #pragma unroll
        for (int mi = 0; mi < 4; ++mi)
            a[mi] = *(const short8*)(&As[(wr * 64 + mi * 16 + c) * 32 + g * 8]);
        #pragma unroll
        for (int ni = 0; ni < 2; ++ni)
            bfr[ni] = *(const short8*)(&Bs[(wc * 32 + ni * 16 + c) * 32 + g * 8]);
        #pragma unroll
        for (int mi = 0; mi < 4; ++mi)
            #pragma unroll
            for (int ni = 0; ni < 2; ++ni)
                acc[mi][ni] = MFMA16(a[mi], bfr[ni], acc[mi][ni], 0, 0, 0);
    }

    #pragma unroll
    for (int mi = 0; mi < 4; ++mi) {
        #pragma unroll
        for (int ni = 0; ni < 2; ++ni) {
            const int n = bn + wc * 32 + ni * 16 + c;
            const float bias = bp[n];
            float v[4];
            #pragma unroll
            for (int r = 0; r < 4; ++r)
                v[r] = fmaxf(acc[mi][ni][r] + bias, 0.0f);
            const int mbase = bm + wr * 64 + mi * 16 + 4 * g;
            if constexpr (HEADOUT) {
                const int bb = mbase >> 11, ss = mbase & 2047;
                const int hh = n >> 6, hd = n & 63;
                if (z == 2) {
                    // V head-transposed: Vt[(bb*H+hh)][hd][ss..ss+3]
                    union { ushort4 u; unsigned short s[4]; } pk;
                    #pragma unroll
                    for (int r = 0; r < 4; ++r) pk.s[r] = f32_to_bf16_bits(v[r]);
                    *reinterpret_cast<ushort4*>(
                        Hout + (size_t)2 * HEADMAT +
                        ((size_t)(bb * Hc + hh) * HDc + hd) * Sc + ss) = pk.u;
                } else {
                    #pragma unroll
                    for (int r = 0; r < 4; ++r)
                        Hout[(size_t)z * HEADMAT +
                             (((size_t)(bb * Hc + hh) * Sc + ss + r) * HDc + hd)] =
                            f32_to_bf16_bits(v[r]);
                }
            } else {
                #pragma unroll
                for (int r = 0; r < 4; ++r)
                    Yf[(size_t)(mbase + r) * 512 + n] = v[r];
            }
        }
    }
}

// ---------------------------------------------------------------------------
// Split-K flash attention, v11: R13-verified 32x32 structure with the V path
// moved OFF the LDS pipe. PV A-fragments are direct global ushort8 loads from
// head-transposed Vt[b,h][64][S]:
//   va0[e] = Vt[r32][k0+8hi+e]      (keys 0-15,  d 0-31)   etc.
// Removes per-iter 4 ds_write_b128 + 64 ds_read_u16 + ~64 addr VALU -- the
// per-CU LDS-pipe contention that pinned R7-R14 at 62-77us. Lanes 0-31/32-63
// share the same 32 L2 lines per load instr (~4KB/instr sector traffic).
// LDS now only holds the end-of-loop combine overlay.
// ---------------------------------------------------------------------------
__global__ __launch_bounds__(256)
void attn_mfma(const short* __restrict__ Qh, const short* __restrict__ Kh,
               const short* __restrict__ Vt, const int* __restrict__ mask,
               unsigned short* __restrict__ Ob)
{
    // per-wave overlay: Lacc[64][33] f32 (8448B); Lml 256B/wave
    __shared__ __align__(16) char smem[4 * 8448 + 4 * 256];

    const int lane = threadIdx.x & 63;
    const int wave = threadIdx.x >> 6;
    const int bid  = blockIdx.x;                    // 1024 blocks
    const int swz  = (bid & 7) * 128 + (bid >> 3);  // XCD-chunked, bijective
    const int t    = swz & 63;
    const int h    = (swz >> 6) & 7;
    const int b    = swz >> 9;
    const int q0   = t * 32;
    const int r32  = lane & 31;
    const int hi   = lane >> 5;

    char*  wreg = smem + wave * 8448;
    float* Lml  = (float*)(smem + 4 * 8448 + wave * 256);

    const size_t headoff = (size_t)(b * Hc + h) * Sc * HDc;
    const short* Qp = Qh + headoff;
    const short* Kp = Kh + headoff;
    const short* Vp = Vt + headoff;                 // [64][Sc] within head
    const int* mb = mask + b * Sc;

    // first unmasked key (block-uniform)
    int fb = Sc;
    for (int base = 0; base < Sc; base += 64) {
        unsigned long long bal = __ballot(mb[base + lane] != 0);
        if (bal) { fb = base + (__ffsll(bal) - 1); break; }
    }
    const int kmax = (fb <= q0) ? (q0 + 32) : Sc;
    const int kend = (kmax + 31) & ~31;
    const int nT   = kend >> 5;
    const int tpw  = (nT + 3) >> 2;
    const int kbeg = wave * tpw * 32;
    const int kfin = min(kend, kbeg + tpw * 32);

    // Q fragments (B-operand): Q[q=r32][d = 16j + 8hi + e]
    short8 qf[4];
    #pragma unroll
    for (int j = 0; j < 4; ++j)
        qf[j] = *(const short8*)(Qp + (size_t)(q0 + r32) * HDc + j * 16 + hi * 8);

    f32x16 acc0 = {0,0,0,0,0,0,0,0,0,0,0,0,0,0,0,0};
    f32x16 acc1 = {0,0,0,0,0,0,0,0,0,0,0,0,0,0,0,0};
    float m = -1e30f, l = 0.0f;

    // per-lane V-fragment row bases (d = r32 and 32+r32)
    const short* vrow0 = Vp + (size_t)r32 * Sc + 8 * hi;
    const short* vrow1 = Vp + (size_t)(32 + r32) * Sc + 8 * hi;

    for (int k0 = kbeg; k0 < kfin; k0 += 32) {
        // --- V fragments: direct global loads (consumed at the bottom;
        //     L2 latency hides under QK^T + softmax)
        const short8 va0 = *(const short8*)(vrow0 + k0);
        const short8 va1 = *(const short8*)(vrow0 + k0 + 16);
        const short8 vb0 = *(const short8*)(vrow1 + k0);
        const short8 vb1 = *(const short8*)(vrow1 + k0 + 16);

        // --- K fragments (A-operand): K[key=r32][d = 16j + 8hi + e]
        f32x16 s = {0,0,0,0,0,0,0,0,0,0,0,0,0,0,0,0};
        #pragma unroll
        for (int j = 0; j < 4; ++j) {
            const short8 kf =
                *(const short8*)(Kp + (size_t)(k0 + r32) * HDc + j * 16 + hi * 8);
            s = MFMA32(kf, qf[j], s, 0, 0, 0);
        }

        // --- padding-mask bits (ballot -> wave-uniform word)
        const unsigned long long bal = __ballot(mb[k0 + r32] != 0);
        const unsigned int mloc = ((unsigned int)bal) >> (4 * hi);

        float e[16];
        float tmax = -1e30f;
        if (k0 + 31 > q0) {   // diagonal tile: causal compares needed
            #pragma unroll
            for (int r = 0; r < 16; ++r) {
                const int cr0 = (r & 3) + 8 * (r >> 2);
                float ev = s[r] * SC2;
                if (!((mloc >> cr0) & 1))            ev -= NEG2;
                if (k0 + cr0 + 4 * hi > q0 + r32)    ev -= NEG2;
                e[r] = ev;
                tmax = fmaxf(tmax, ev);
            }
        } else {
            #pragma unroll
            for (int r = 0; r < 16; ++r) {
                const int cr0 = (r & 3) + 8 * (r >> 2);
                float ev = s[r] * SC2;
                if (!((mloc >> cr0) & 1))            ev -= NEG2;
                e[r] = ev;
                tmax = fmaxf(tmax, ev);
            }
        }
        tmax = fmaxf(tmax, __shfl_xor(tmax, 32));   // full-row max

        if (__any(tmax > m)) {
            const float mn   = fmaxf(m, tmax);
            const float corr = __builtin_exp2f(m - mn);
            m = mn; l *= corr;
            acc0 *= corr;            // q = lane&31: lane-local rescale
            acc1 *= corr;
        }

        float ps = 0.f;
        #pragma unroll
        for (int r = 0; r < 16; ++r) {
            e[r] = __builtin_exp2f(e[r] - m);   // e[] now holds p
            ps += e[r];
        }
        l += ps;   // own-half partial; cross-half added at end

        // --- pack P pairs and exchange across lane-halves
        const unsigned int A0 = pkbf(e[0],  e[1]),  B0 = pkbf(e[2],  e[3]);
        const unsigned int C0 = pkbf(e[4],  e[5]),  D0 = pkbf(e[6],  e[7]);
        const unsigned int A1 = pkbf(e[8],  e[9]),  B1 = pkbf(e[10], e[11]);
        const unsigned int C1 = pkbf(e[12], e[13]), D1 = pkbf(e[14], e[15]);
        const unsigned int A0s = (unsigned int)__shfl_xor((int)A0, 32);
        const unsigned int B0s = (unsigned int)__shfl_xor((int)B0, 32);
        const unsigned int C0s = (unsigned int)__shfl_xor((int)C0, 32);
        const unsigned int D0s = (unsigned int)__shfl_xor((int)D0, 32);
        const unsigned int A1s = (unsigned int)__shfl_xor((int)A1, 32);
        const unsigned int B1s = (unsigned int)__shfl_xor((int)B1, 32);
        const unsigned int C1s = (unsigned int)__shfl_xor((int)C1, 32);
        const unsigned int D1s = (unsigned int)__shfl_xor((int)D1, 32);

        union { unsigned int u[4]; short8 s8; } P0, P1;
        P0.u[0] = hi ? C0s : A0;  P0.u[1] = hi ? D0s : B0;
        P0.u[2] = hi ? C0  : A0s; P0.u[3] = hi ? D0  : B0s;
        P1.u[0] = hi ? C1s : A1;  P1.u[1] = hi ? D1s : B1;
        P1.u[2] = hi ? C1  : A1s; P1.u[3] = hi ? D1  : B1s;

        // --- PV: O^T += V^T_frag x P_frag (V frags already in registers)
        acc0 = MFMA32(va0, P0.s8, acc0, 0, 0, 0);
        acc0 = MFMA32(va1, P1.s8, acc0, 0, 0, 0);
        acc1 = MFMA32(vb0, P0.s8, acc1, 0, 0, 0);
        acc1 = MFMA32(vb1, P1.s8, acc1, 0, 0, 0);
    }

    l += __shfl_xor(l, 32);   // full-row denominator for this wave

    // dump partials into OWN overlay region
    {
        float* Lacc = (float*)wreg;   // [64][33]
        #pragma unroll
        for (int r = 0; r < 16; ++r) {
            Lacc[lane * 33 + r]      = acc0[r];
            Lacc[lane * 33 + 16 + r] = acc1[r];
        }
        if (lane < 32) { Lml[lane] = m; Lml[32 + lane] = l; }
    }
    __syncthreads();

    // combine: per-lane weights (q = r32); wave w handles regs [8w, 8w+8)
    float mu[4], lu[4], M = -1e30f;
    #pragma unroll
    for (int u = 0; u < 4; ++u) {
        const float* LmlU = (const float*)(smem + 4 * 8448 + u * 256);
        mu[u] = LmlU[r32];
        lu[u] = LmlU[32 + r32];
        M = fmaxf(M, mu[u]);
    }
    float wgt[4], L = 0.f;
    #pragma unroll
    for (int u = 0; u < 4; ++u) {
        wgt[u] = __builtin_exp2f(mu[u] - M);
        L += wgt[u] * lu[u];
    }
    const float invL = 1.0f / L;

    #pragma unroll
    for (int jj = 0; jj < 8; ++jj) {
        const int j = wave * 8 + jj;
        float o = 0.f;
        #pragma unroll
        for (int u = 0; u < 4; ++u)
            o += wgt[u] * ((const float*)(smem + u * 8448))[lane * 33 + j];
        const int j16 = j & 15;
        const int d = (j16 & 3) + 8 * (j16 >> 2) + 4 * hi + 32 * (j >> 4);
        Ob[(size_t)(b * Sc + q0 + r32) * Dc + h * HDc + d] =
            f32_to_bf16_bits(o * invL);
    }
}

// ---------------------------------------------------------------------------
extern "C" void kernel_launch(void* const* d_in, const int* in_sizes, int n_in,
                              void* d_out, int out_size, void* d_ws, size_t ws_size,
                              hipStream_t stream) {
    const float* x  = (const float*)d_in[0];
    const int* mask = (const int*)d_in[1];
    const float* Wq = (const float*)d_in[2];
    const float* bq = (const float*)d_in[3];
    const float* Wk = (const float*)d_in[4];
    const float* bk = (const float*)d_in[5];
    const float* Wv = (const float*)d_in[6];
    const float* bv = (const float*)d_in[7];
    const float* Wo = (const float*)d_in[8];
    const float* bo = (const float*)d_in[9];
    float* out = (float*)d_out;   // reference output dtype is float32

    unsigned short* Xb = (unsigned short*)d_ws;          // 4 MB
    unsigned short* Wt = Xb + (size_t)Mtot * 512;        // 2 MB
    unsigned short* Qh = Wt + (size_t)4 * 512 * 512;     // head-major
    unsigned short* Kh = Qh + HEADMAT;                   // head-major
    unsigned short* Vt = Kh + HEADMAT;                   // head-TRANSPOSED
    unsigned short* Ob = Vt + HEADMAT;

    convert_x<<<dim3((Mtot * 512) / 1024), dim3(256), 0, stream>>>(
        x, Xb, Mtot * 512);
    transpose_w<<<dim3(8, 8, 4), dim3(256), 0, stream>>>(Wq, Wk, Wv, Wo, Wt);
    gemm_tile<true><<<dim3(8, Mtot / 128, 3), dim3(256), 0, stream>>>(
        Xb, Wt, bq, bk, bv, Qh, nullptr);
    attn_mfma<<<dim3(1024), dim3(256), 0, stream>>>(
        (const short*)Qh, (const short*)Kh, (const short*)Vt, mask, Ob);
    gemm_tile<false><<<dim3(8, Mtot / 128, 1), dim3(256), 0, stream>>>(
        Ob, Wt + (size_t)3 * 512 * 512, bo, bo, bo, nullptr, out);
}